// Round 2
// baseline (386.789 us; speedup 1.0000x reference)
//
#include <hip/hip_runtime.h>

typedef __attribute__((ext_vector_type(8))) short short8;
typedef __attribute__((ext_vector_type(4))) short short4_t;
typedef __attribute__((ext_vector_type(4))) float float4_t;

#define NTOK 4096
#define CDIM 256
#define BPB (NTOK * CDIM)               /* elements per batch per tensor */
#define C1 0.0901684400555602f          /* log2(e) / sqrt(256) */

__device__ inline float bf2f(short s) {
    return __uint_as_float(((unsigned)(unsigned short)s) << 16);
}
__device__ inline short f2bf(float f) {
    unsigned u = __float_as_uint(f);
    return (short)((u + 0x7fffu + ((u >> 16) & 1u)) >> 16);
}

// ---------------------------------------------------------------------------
// Dtype sniff: x ~ N(0,1). If buffer is bf16, bits[14:7] of each dword is a
// bf16 exponent (~always in [100,140]); if fp32, those bits are mantissa
// noise (~16% hit). flag=1 -> bf16.
// ---------------------------------------------------------------------------
__global__ void sniff_dtype(const unsigned* __restrict__ x, int* __restrict__ flag) {
    __shared__ int cnt;
    if (threadIdx.x == 0) cnt = 0;
    __syncthreads();
    int local = 0;
    for (int i = threadIdx.x; i < 1024; i += 256) {
        unsigned e = (x[i] >> 7) & 0xffu;
        if (e >= 100u && e <= 140u) local++;
    }
    atomicAdd(&cnt, local);
    __syncthreads();
    if (threadIdx.x == 0) flag[0] = (cnt >= 512) ? 1 : 0;
}

// ---------------------------------------------------------------------------
// QKV projection body. Out[n][d] = sum_c X[c][n] * W[d][c] + b[d]
// Q,K stored [n][d]; V stored transposed [d][n].
// ---------------------------------------------------------------------------
template <bool ISBF>
__device__ __forceinline__ void qkv_body(
    int b, const void* xv,
    const void* Wqv, const void* bqv,
    const void* Wkv, const void* bkv,
    const void* Wvv, const void* bvv,
    short* qdst, short* kdst, short* vtdst)
{
    const int n0 = blockIdx.x * 64;
    const int tid = threadIdx.x;
    const int w = tid >> 6, lane = tid & 63, l15 = lane & 15, qd = lane >> 4;

    __shared__ short xt[64 * 264];  // XT[n][c], stride 264

    {   // stage X tile transposed: thread tid owns channel c = tid
        const int c = tid;
        const size_t xb = (size_t)b * CDIM * NTOK + (size_t)c * NTOK + n0;
        if (ISBF) {
            const short* x = (const short*)xv;
            #pragma unroll
            for (int i = 0; i < 8; ++i) {
                short8 v = *(const short8*)(x + xb + i * 8);
                #pragma unroll
                for (int j = 0; j < 8; ++j) xt[(i * 8 + j) * 264 + c] = v[j];
            }
        } else {
            const float* x = (const float*)xv;
            #pragma unroll
            for (int i = 0; i < 16; ++i) {
                float4 v = *(const float4*)(x + xb + i * 4);
                xt[(i * 4 + 0) * 264 + c] = f2bf(v.x);
                xt[(i * 4 + 1) * 264 + c] = f2bf(v.y);
                xt[(i * 4 + 2) * 264 + c] = f2bf(v.z);
                xt[(i * 4 + 3) * 264 + c] = f2bf(v.w);
            }
        }
    }
    __syncthreads();

    // A-frags: rows n0+16w+l15, k = s*32 + qd*8 + j
    short8 afrag[8];
    #pragma unroll
    for (int s = 0; s < 8; ++s)
        afrag[s] = *(const short8*)&xt[(16 * w + l15) * 264 + s * 32 + qd * 8];

    const void* Ws[3] = { Wqv, Wkv, Wvv };
    const void* bs[3] = { bqv, bkv, bvv };
    short* dsts[2] = { qdst, kdst };

    for (int wi = 0; wi < 3; ++wi) {
        for (int dt = 0; dt < 16; ++dt) {
            const int drow = 16 * dt + l15;
            float4_t acc = {0.f, 0.f, 0.f, 0.f};
            #pragma unroll
            for (int s = 0; s < 8; ++s) {
                short8 bfrag;
                if (ISBF) {
                    bfrag = *(const short8*)((const short*)Ws[wi] + drow * 256 + s * 32 + qd * 8);
                } else {
                    const float* Wf = (const float*)Ws[wi];
                    float4 a  = *(const float4*)(Wf + drow * 256 + s * 32 + qd * 8);
                    float4 c4 = *(const float4*)(Wf + drow * 256 + s * 32 + qd * 8 + 4);
                    bfrag[0] = f2bf(a.x);  bfrag[1] = f2bf(a.y);
                    bfrag[2] = f2bf(a.z);  bfrag[3] = f2bf(a.w);
                    bfrag[4] = f2bf(c4.x); bfrag[5] = f2bf(c4.y);
                    bfrag[6] = f2bf(c4.z); bfrag[7] = f2bf(c4.w);
                }
                acc = __builtin_amdgcn_mfma_f32_16x16x32_bf16(afrag[s], bfrag, acc, 0, 0, 0);
            }
            const float bias = ISBF ? bf2f(((const short*)bs[wi])[drow])
                                    : ((const float*)bs[wi])[drow];
            if (wi < 2) {
                short* dst = dsts[wi];
                #pragma unroll
                for (int r = 0; r < 4; ++r) {
                    const int n = n0 + 16 * w + 4 * qd + r;
                    dst[(size_t)n * 256 + drow] = f2bf(acc[r] + bias);
                }
            } else {
                short4_t pk;
                #pragma unroll
                for (int r = 0; r < 4; ++r) pk[r] = f2bf(acc[r] + bias);
                const int n = n0 + 16 * w + 4 * qd;
                *(short4_t*)(vtdst + (size_t)drow * NTOK + n) = pk;
            }
        }
    }
}

__global__ __launch_bounds__(256, 1) void qkv_proj(
    int b0, const void* xv, const void* Wq, const void* bq,
    const void* Wk, const void* bk, const void* Wv, const void* bv,
    const int* __restrict__ flag,
    short* qbase, short* kbase, short* vtbase)
{
    const int bl = blockIdx.y, b = b0 + bl;
    short* qdst  = qbase  + (size_t)b  * BPB;   // absolute batch
    short* kdst  = kbase  + (size_t)bl * BPB;   // chunk-local
    short* vtdst = vtbase + (size_t)bl * BPB;
    if (flag[0]) qkv_body<true >(b, xv, Wq, bq, Wk, bk, Wv, bv, qdst, kdst, vtdst);
    else         qkv_body<false>(b, xv, Wq, bq, Wk, bk, Wv, bv, qdst, kdst, vtdst);
}

// ---------------------------------------------------------------------------
// Flash attention: BM=64 per wg (4 waves x 16 rows), BN=64 per iteration.
// K tile [64][264] and VT tile [256][72] overlay the same LDS region.
// ---------------------------------------------------------------------------
__global__ __launch_bounds__(256, 1) void flash_att(
    int b0, const short* qbase, const short* kbase, const short* vtbase,
    const int* __restrict__ flag, void* outv)
{
    const int qt = blockIdx.x;
    const int bl = blockIdx.y, b = b0 + bl;
    const int q0 = qt * 64;
    const int tid = threadIdx.x;
    const int w = tid >> 6, lane = tid & 63, l15 = lane & 15, qd = lane >> 4;

    __shared__ short smem[18432 + 4608];
    short* kv   = smem;           // K [64][264] or VT [256][72] (overlaid)
    short* pbuf = smem + 18432;   // P strips: [wave][16][72]

    const short* Q  = qbase  + (size_t)b  * BPB;
    const short* K  = kbase  + (size_t)bl * BPB;
    const short* VT = vtbase + (size_t)bl * BPB;

    // hoisted Q A-frags (must complete before epilogue may overwrite Q==out)
    short8 qf[8];
    {
        const size_t qrow = (size_t)(q0 + 16 * w + l15) * 256;
        #pragma unroll
        for (int s = 0; s < 8; ++s)
            qf[s] = *(const short8*)(Q + qrow + s * 32 + qd * 8);
    }

    float4_t oacc[16];
    #pragma unroll
    for (int dt = 0; dt < 16; ++dt) oacc[dt] = {0.f, 0.f, 0.f, 0.f};
    float m_run[4] = { -INFINITY, -INFINITY, -INFINITY, -INFINITY };
    float l_run[4] = { 0.f, 0.f, 0.f, 0.f };

    for (int kt = 0; kt < 64; ++kt) {
        const int k0 = kt * 64;
        __syncthreads();  // prior PV reads of kv done before K overwrite

        #pragma unroll
        for (int i = 0; i < 8; ++i) {   // stage K tile [64][256] -> kv[64][264]
            const int id = i * 256 + tid;
            const int r = id >> 5, j = id & 31;
            short8 v = *(const short8*)(K + (size_t)(k0 + r) * 256 + j * 8);
            *(short8*)&kv[r * 264 + j * 8] = v;
        }
        __syncthreads();

        // ---- S = Q K^T ----
        float4_t sacc[4];
        #pragma unroll
        for (int tn = 0; tn < 4; ++tn) {
            sacc[tn] = {0.f, 0.f, 0.f, 0.f};
            #pragma unroll
            for (int s = 0; s < 8; ++s) {
                short8 bf = *(const short8*)&kv[(tn * 16 + l15) * 264 + s * 32 + qd * 8];
                sacc[tn] = __builtin_amdgcn_mfma_f32_16x16x32_bf16(qf[s], bf, sacc[tn], 0, 0, 0);
            }
        }

        // ---- online softmax (row = 4qd + r, owned by the 16-lane quad) ----
        float p[4][4], alpha[4];
        #pragma unroll
        for (int r = 0; r < 4; ++r) {
            float m = sacc[0][r];
            #pragma unroll
            for (int tn = 1; tn < 4; ++tn) m = fmaxf(m, sacc[tn][r]);
            #pragma unroll
            for (int msk = 1; msk < 16; msk <<= 1)
                m = fmaxf(m, __shfl_xor(m, msk, 64));
            const float mnew = fmaxf(m_run[r], m);
            alpha[r] = exp2f((m_run[r] - mnew) * C1);
            m_run[r] = mnew;
            float lsum = 0.f;
            #pragma unroll
            for (int tn = 0; tn < 4; ++tn) {
                const float pv = exp2f((sacc[tn][r] - mnew) * C1);
                p[tn][r] = pv;
                lsum += pv;
            }
            #pragma unroll
            for (int msk = 1; msk < 16; msk <<= 1)
                lsum += __shfl_xor(lsum, msk, 64);
            l_run[r] = l_run[r] * alpha[r] + lsum;
        }
        #pragma unroll
        for (int dt = 0; dt < 16; ++dt) {
            #pragma unroll
            for (int r = 0; r < 4; ++r) oacc[dt][r] *= alpha[r];
        }
        #pragma unroll
        for (int tn = 0; tn < 4; ++tn) {
            #pragma unroll
            for (int r = 0; r < 4; ++r)
                pbuf[(w * 16 + 4 * qd + r) * 72 + tn * 16 + l15] = f2bf(p[tn][r]);
        }

        __syncthreads();  // all kv (K) reads done before VT overwrite

        #pragma unroll
        for (int i = 0; i < 8; ++i) {   // stage VT tile [256][64] -> kv[256][72]
            const int id = i * 256 + tid;
            const int d = id >> 3, j = id & 7;
            short8 v = *(const short8*)(VT + (size_t)d * NTOK + k0 + j * 8);
            *(short8*)&kv[d * 72 + j * 8] = v;
        }
        __syncthreads();

        // ---- O += P V ----
        short8 pa[2];
        #pragma unroll
        for (int ks = 0; ks < 2; ++ks)
            pa[ks] = *(const short8*)&pbuf[(w * 16 + l15) * 72 + ks * 32 + qd * 8];
        #pragma unroll
        for (int dt = 0; dt < 16; ++dt) {
            #pragma unroll
            for (int ks = 0; ks < 2; ++ks) {
                short8 bf = *(const short8*)&kv[(dt * 16 + l15) * 72 + ks * 32 + qd * 8];
                oacc[dt] = __builtin_amdgcn_mfma_f32_16x16x32_bf16(pa[ks], bf, oacc[dt], 0, 0, 0);
            }
        }
    }

    // epilogue
    const int isbf = flag[0];
    float inv[4];
    #pragma unroll
    for (int r = 0; r < 4; ++r) inv[r] = 1.0f / l_run[r];
    #pragma unroll
    for (int dt = 0; dt < 16; ++dt) {
        #pragma unroll
        for (int r = 0; r < 4; ++r) {
            const size_t o =
                (size_t)(b * NTOK + q0 + 16 * w + 4 * qd + r) * 256 + dt * 16 + l15;
            const float val = oacc[dt][r] * inv[r];
            if (isbf) ((short*)outv)[o] = f2bf(val);
            else      ((float*)outv)[o] = val;
        }
    }
}

extern "C" void kernel_launch(void* const* d_in, const int* in_sizes, int n_in,
                              void* d_out, int out_size, void* d_ws, size_t ws_size,
                              hipStream_t stream)
{
    const size_t HDR = 256;                       // flag header
    const size_t TB  = (size_t)BPB * 2;           // bytes per batch per tensor (bf16)
    const size_t avail = ws_size > HDR ? ws_size - HDR : 0;

    // host-side layout decision — depends only on ws_size (constant across
    // calls, so graph capture sees identical work every time)
    const bool q_in_ws = avail >= 12 * TB;        // K(4) + VT(4) + Q(4)
    int nb = 4;
    if (!q_in_ws) {
        size_t per = 2 * TB;                      // K + VT per batch
        size_t fit = avail / per;
        nb = fit >= 4 ? 4 : (fit < 1 ? 1 : (int)fit);
    }

    int*   flag   = (int*)d_ws;
    short* kbase  = (short*)((char*)d_ws + HDR);
    short* vtbase = kbase + (size_t)nb * BPB;
    short* qbase  = q_in_ws ? (vtbase + (size_t)nb * BPB) : (short*)d_out;

    sniff_dtype<<<1, 256, 0, stream>>>((const unsigned*)d_in[0], flag);

    for (int b0 = 0; b0 < 4; b0 += nb) {
        const int nbc = (4 - b0) < nb ? (4 - b0) : nb;
        qkv_proj<<<dim3(64, nbc), 256, 0, stream>>>(
            b0, d_in[0], d_in[1], d_in[2], d_in[3], d_in[4], d_in[5], d_in[6],
            flag, qbase, kbase, vtbase);
        flash_att<<<dim3(64, nbc), 256, 0, stream>>>(
            b0, qbase, kbase, vtbase, flag, d_out);
    }
}